// Round 2
// baseline (217.367 us; speedup 1.0000x reference)
//
#include <hip/hip_runtime.h>
#include <hip/hip_cooperative_groups.h>

namespace cg = cooperative_groups;

#define DD 128
#define NN 512

// ---------------------------------------------------------------------------
// Single cooperative kernel, 256 blocks x 512 threads. Block bl -> batch
// b = bl>>6, rows [bl*8, bl*8+8) (global row space, 2048 rows).
//
//  entry:   issue adj row loads (wave wv = row wv), overlap phase 0.
//  phase 0: W1 matvec FINE-SPLIT across grid. Reduction domain per (b,d):
//           512 virtual rows (vr): 0-127 E0@W1a, 128-255 nc@W1b,
//           256-383 te[t[b]]@W1c  (-> cb), 384-511 (E1-E0)@W1a (-> v1).
//           Block (b, kc=bl&63) handles vr [kc*8, kc*8+8): 2 loads/thread.
//           W1 traffic: ~1 MB total (was 50 MB redundant L2 reads).
//  sync1
//  phase P': reduce 64 partials/batch from ws_part (L2) -> s_cb, s_v1.
//  phase A: popcount -> p[r];  phase B: preHf partials;  phase C: relu+W2/Wc
//           projection -> lj to ws (cross-block), li+bc to LDS (local only).
//  sync2
//  phase W: block writes its own 8 out rows: li from LDS, lj[512] from L2.
//           64 B/thread contiguous stores, HBM-bound.
// ---------------------------------------------------------------------------
__global__ __launch_bounds__(512) void fused_kernel(
    const int* __restrict__ adj,
    const int* __restrict__ tt,
    const float* __restrict__ time_embed,
    const float* __restrict__ no_cond,
    const float* __restrict__ edge_embed,
    const float* __restrict__ W1,
    const float* __restrict__ b1,
    const float* __restrict__ W2,
    const float* __restrict__ b2,
    const float* __restrict__ Wc,
    const float* __restrict__ bc,
    float* __restrict__ out,
    float* __restrict__ ws_lj,    // [2048*2]
    float* __restrict__ ws_part)  // [4*64*128]
{
    __shared__ float sP[8 * 8 * DD];   // 32 KB phase-B partials
    __shared__ float sRA[512];
    __shared__ float sRB[512];
    __shared__ float s_cb[DD];
    __shared__ float s_v1[DD];
    __shared__ float s_p[8];
    __shared__ float s_li[16];

    const int t = threadIdx.x;
    const int lane = t & 63;
    const int wv = t >> 6;            // wave id 0..7
    const int bl = blockIdx.x;
    const int b = bl >> 6;            // batch
    const int kc = bl & 63;           // phase-0 vr chunk

    cg::grid_group grid = cg::this_grid();

    // --- entry: adj loads for phase A (wave wv owns row bl*8 + wv) ---
    const int4* abase = (const int4*)(adj + (size_t)(bl * 8 + wv) * NN);
    int4 a0 = abase[lane];
    int4 a1 = abase[lane + 64];

    // --- phase 0: 2 W1 terms per thread.  d = t&127, s = t>>7 -> vr pair ---
    {
        const int d = t & 127;
        const int s = t >> 7;
        const int vr0 = kc * 8 + s * 2;   // chunk never straddles 128/256/384
        float acc;
        if (vr0 < 128) {
            acc = edge_embed[vr0] * W1[vr0 * DD + d];
            acc = fmaf(edge_embed[vr0 + 1], W1[(vr0 + 1) * DD + d], acc);
        } else if (vr0 < 256) {
            acc = no_cond[vr0 - 128] * W1[vr0 * DD + d];
            acc = fmaf(no_cond[vr0 - 127], W1[(vr0 + 1) * DD + d], acc);
        } else if (vr0 < 384) {
            const float* teb = time_embed + (size_t)tt[b] * DD;
            acc = teb[vr0 - 256] * W1[vr0 * DD + d];
            acc = fmaf(teb[vr0 - 255], W1[(vr0 + 1) * DD + d], acc);
        } else {
            const int k = vr0 - 384;
            acc = (edge_embed[DD + k] - edge_embed[k]) * W1[k * DD + d];
            acc = fmaf(edge_embed[DD + k + 1] - edge_embed[k + 1],
                       W1[(k + 1) * DD + d], acc);
        }
        sRA[t] = acc;
    }

    // --- phase A: popcount (adj loads have landed by now) ---
    {
        int s = a0.x + a0.y + a0.z + a0.w + a1.x + a1.y + a1.z + a1.w;
#pragma unroll
        for (int off = 32; off; off >>= 1) s += __shfl_xor(s, off, 64);
        if (lane == 0) s_p[wv] = (float)s * (1.0f / (float)NN);
    }
    __syncthreads();
    if (t < DD)
        ws_part[(b * 64 + kc) * DD + t] =
            sRA[t] + sRA[t + 128] + sRA[t + 256] + sRA[t + 384];

    __threadfence();
    grid.sync();

    // --- phase P': reduce my batch's partials. kc 0..47 -> cb, 48..63 -> v1 ---
    {
        const int d = t & 127;
        const int g = t >> 7;         // 0..3
        const float* base = ws_part + (size_t)b * 64 * DD;
        float sc = 0.f, sv = 0.f;
#pragma unroll
        for (int m = 0; m < 12; ++m) sc += base[(g * 12 + m) * DD + d];
#pragma unroll
        for (int m = 0; m < 4; ++m)  sv += base[(48 + g * 4 + m) * DD + d];
        sRA[t] = sc;
        sRB[t] = sv;
    }
    __syncthreads();
    if (t < DD) {
        s_cb[t] = sRA[t] + sRA[t + 128] + sRA[t + 256] + sRA[t + 384] + b1[t];
        s_v1[t] = sRB[t] + sRB[t + 128] + sRB[t + 256] + sRB[t + 384];
    }
    __syncthreads();

    float p[8];
#pragma unroll
    for (int r = 0; r < 8; ++r) p[r] = s_p[r];

    // --- phase B: partial matvec. thread = (2 cols c0, d-chunk dh of 16) ---
    const int cg_ = t & 63;
    const int dh = t >> 6;            // 0..7
    const int c0 = cg_ * 2;
    float acc[8][2];
#pragma unroll
    for (int r = 0; r < 8; ++r) { acc[r][0] = 0.f; acc[r][1] = 0.f; }

    const float2* W2v = (const float2*)W2;
#pragma unroll
    for (int i = 0; i < 16; ++i) {
        const int d = dh * 16 + i;
        float2 w = W2v[(d * DD + c0) >> 1];
        float cbd = s_cb[d];
        float v1d = s_v1[d];
#pragma unroll
        for (int r = 0; r < 8; ++r) {
            float h = fmaxf(fmaf(p[r], v1d, cbd), 0.f);
            acc[r][0] = fmaf(h, w.x, acc[r][0]);
            acc[r][1] = fmaf(h, w.y, acc[r][1]);
        }
    }
#pragma unroll
    for (int r = 0; r < 8; ++r)
        *(float2*)&sP[(r * 8 + dh) * DD + c0] = make_float2(acc[r][0], acc[r][1]);
    __syncthreads();

    // --- phase C: combine. wave wv -> row wv; lane -> cols lane, lane+64 ---
    {
        float s0 = 0.f, s1 = 0.f;
#pragma unroll
        for (int k = 0; k < 8; ++k) {
            const float* rowp = &sP[(wv * 8 + k) * DD];
            s0 += rowp[lane];
            s1 += rowp[lane + 64];
        }
        float f0 = fmaxf(s0 + b2[lane], 0.f);
        float f1 = fmaxf(s1 + b2[lane + 64], 0.f);

        const float2* Wc2 = (const float2*)Wc;
        float2 wa0 = Wc2[lane];
        float2 wa1 = Wc2[lane + 64];
        float2 wb0 = Wc2[DD + lane];
        float2 wb1 = Wc2[DD + lane + 64];

        float li0 = f0 * wa0.x + f1 * wa1.x;
        float li1 = f0 * wa0.y + f1 * wa1.y;
        float lj0 = f0 * wb0.x + f1 * wb1.x;
        float lj1 = f0 * wb0.y + f1 * wb1.y;

#pragma unroll
        for (int off = 32; off; off >>= 1) {
            li0 += __shfl_xor(li0, off, 64);
            li1 += __shfl_xor(li1, off, 64);
            lj0 += __shfl_xor(lj0, off, 64);
            lj1 += __shfl_xor(lj1, off, 64);
        }
        if (lane == 0) {
            *(float2*)&ws_lj[(bl * 8 + wv) * 2] = make_float2(lj0, lj1);
            s_li[wv * 2]     = li0 + bc[0];   // bc folded here
            s_li[wv * 2 + 1] = li1 + bc[1];
        }
    }

    __threadfence();
    grid.sync();

    // --- phase W: write my 8 rows. thread = (row r, 8 j's = 64 B stores) ---
    {
        const int r = t >> 6;
        const int j0 = lane * 8;
        const float la = s_li[r * 2];
        const float lb = s_li[r * 2 + 1];
        const float* ljp = ws_lj + ((size_t)b * NN + j0) * 2;
        float4 L0 = *(const float4*)(ljp + 0);
        float4 L1 = *(const float4*)(ljp + 4);
        float4 L2 = *(const float4*)(ljp + 8);
        float4 L3 = *(const float4*)(ljp + 12);

        size_t base = ((size_t)(bl * 8 + r) * NN + j0) * 2;
        *(float4*)&out[base + 0]  = make_float4(la + L0.x, lb + L0.y, la + L0.z, lb + L0.w);
        *(float4*)&out[base + 4]  = make_float4(la + L1.x, lb + L1.y, la + L1.z, lb + L1.w);
        *(float4*)&out[base + 8]  = make_float4(la + L2.x, lb + L2.y, la + L2.z, lb + L2.w);
        *(float4*)&out[base + 12] = make_float4(la + L3.x, lb + L3.y, la + L3.z, lb + L3.w);
    }
}

extern "C" void kernel_launch(void* const* d_in, const int* in_sizes, int n_in,
                              void* d_out, int out_size, void* d_ws, size_t ws_size,
                              hipStream_t stream) {
    const int*   adj = (const int*)d_in[0];
    const int*   tt  = (const int*)d_in[1];
    const float* te  = (const float*)d_in[2];
    const float* nc  = (const float*)d_in[3];
    const float* ee  = (const float*)d_in[4];
    const float* W1  = (const float*)d_in[5];
    const float* b1  = (const float*)d_in[6];
    const float* W2  = (const float*)d_in[7];
    const float* b2  = (const float*)d_in[8];
    const float* Wc  = (const float*)d_in[9];
    const float* bc  = (const float*)d_in[10];
    float* out = (float*)d_out;

    float* ws      = (float*)d_ws;
    float* ws_lj   = ws;              // 4096 floats
    float* ws_part = ws + 4096;       // 32768 floats

    void* args[] = {&adj, &tt, &te, &nc, &ee, &W1, &b1, &W2, &b2, &Wc, &bc,
                    &out, &ws_lj, &ws_part};
    hipLaunchCooperativeKernel((const void*)fused_kernel, dim3(256), dim3(512),
                               args, 0, stream);
}

// Round 3
// 88.156 us; speedup vs baseline: 2.4657x; 2.4657x over previous
//
#include <hip/hip_runtime.h>

#define DD 128
#define NN 512

// ---------------------------------------------------------------------------
// Kernel 1: fused prep + per-row pipeline. 256 blocks x 512 threads, 8 rows/blk.
//  Entry:   issue adj row loads (1 wave = 1 row, 2x int4/lane) -> overlap P.
//  phase P: cb/v1 matvec over W1, 16-way sliced: thread = (d-group dg of 4
//           cols, slice sl = term x k-chunk). 32 float4 W1 loads/thread,
//           FULLY unrolled (all loads in flight; was 128 serial scalar loads).
//             term0: E0@W1a  term1: nc@W1b  term2: te[t[b]]@W1c  -> cb
//             term3: (E1-E0)@W1a                                  -> v1
//           Reduce 16 slices via LDS (stride-1, conflict-free).
//  phase A: popcount ones per row -> p[r] (wave64 reduce; loads from entry).
//  phase B: preHf[r][c] partials: thread = (2 cols, d-chunk of 16); h
//           recomputed in-register; W2 read once per block, float2/lane.
//  phase C: combine 8 partials (stride-1 b32 LDS reads), relu(+b2), project
//           on Wc -> li/lj; bc folded into li so the writer is pure add.
// ---------------------------------------------------------------------------
__global__ __launch_bounds__(512) void rows_kernel(
    const int* __restrict__ adj,
    const int* __restrict__ tt,
    const float* __restrict__ time_embed,
    const float* __restrict__ no_cond,
    const float* __restrict__ edge_embed,
    const float* __restrict__ W1,
    const float* __restrict__ b1,
    const float* __restrict__ W2,
    const float* __restrict__ b2,
    const float* __restrict__ Wc,
    const float* __restrict__ bc,
    float* __restrict__ ws_li,   // [2048*2]  (bc pre-added)
    float* __restrict__ ws_lj)   // [2048*2]
{
    __shared__ float sP[8 * 8 * DD];   // 32 KB phase-B partials
    __shared__ float s_part[16 * DD];  // 8 KB phase-P partials [slice][d]
    __shared__ float s_cb[DD];
    __shared__ float s_v1[DD];
    __shared__ float s_p[8];

    const int t = threadIdx.x;
    const int lane = t & 63;
    const int wv = t >> 6;            // wave id 0..7
    const int row0 = blockIdx.x * 8;
    const int b = blockIdx.x >> 6;

    // --- phase A issue: wave wv owns adj row row0+wv; loads fly during P ---
    const int4* abase = (const int4*)(adj + (size_t)(row0 + wv) * NN);
    int4 a0 = abase[lane];
    int4 a1 = abase[lane + 64];

    // --- phase P: thread = (dg -> d0..d0+3, sl = term*4 + k-chunk) ---
    {
        const int dg = t & 31;
        const int sl = t >> 5;        // 0..15
        const int d0 = dg * 4;
        const int term = sl >> 2;
        const int k0 = (sl & 3) * 32;
        float4 acc = make_float4(0.f, 0.f, 0.f, 0.f);
        if (term == 0) {
#pragma unroll
            for (int k = 0; k < 32; ++k) {
                float e = edge_embed[k0 + k];
                float4 w = *(const float4*)&W1[(k0 + k) * DD + d0];
                acc.x = fmaf(e, w.x, acc.x);
                acc.y = fmaf(e, w.y, acc.y);
                acc.z = fmaf(e, w.z, acc.z);
                acc.w = fmaf(e, w.w, acc.w);
            }
        } else if (term == 1) {
#pragma unroll
            for (int k = 0; k < 32; ++k) {
                float e = no_cond[k0 + k];
                float4 w = *(const float4*)&W1[(128 + k0 + k) * DD + d0];
                acc.x = fmaf(e, w.x, acc.x);
                acc.y = fmaf(e, w.y, acc.y);
                acc.z = fmaf(e, w.z, acc.z);
                acc.w = fmaf(e, w.w, acc.w);
            }
        } else if (term == 2) {
            const float* teb = time_embed + (size_t)tt[b] * DD;
#pragma unroll
            for (int k = 0; k < 32; ++k) {
                float e = teb[k0 + k];
                float4 w = *(const float4*)&W1[(256 + k0 + k) * DD + d0];
                acc.x = fmaf(e, w.x, acc.x);
                acc.y = fmaf(e, w.y, acc.y);
                acc.z = fmaf(e, w.z, acc.z);
                acc.w = fmaf(e, w.w, acc.w);
            }
        } else {
#pragma unroll
            for (int k = 0; k < 32; ++k) {
                float e = edge_embed[DD + k0 + k] - edge_embed[k0 + k];
                float4 w = *(const float4*)&W1[(k0 + k) * DD + d0];
                acc.x = fmaf(e, w.x, acc.x);
                acc.y = fmaf(e, w.y, acc.y);
                acc.z = fmaf(e, w.z, acc.z);
                acc.w = fmaf(e, w.w, acc.w);
            }
        }
        *(float4*)&s_part[sl * DD + d0] = acc;
    }

    // --- phase A finish: popcount -> p[r] ---
    {
        int s = a0.x + a0.y + a0.z + a0.w + a1.x + a1.y + a1.z + a1.w;
#pragma unroll
        for (int off = 32; off; off >>= 1) s += __shfl_xor(s, off, 64);
        if (lane == 0) s_p[wv] = (float)s * (1.0f / (float)NN);
    }
    __syncthreads();

    if (t < DD) {
        float sc = 0.f, sv = 0.f;
#pragma unroll
        for (int m = 0; m < 12; ++m) sc += s_part[m * DD + t];
#pragma unroll
        for (int m = 12; m < 16; ++m) sv += s_part[m * DD + t];
        s_cb[t] = sc + b1[t];
        s_v1[t] = sv;
    }
    __syncthreads();

    float p[8];
#pragma unroll
    for (int r = 0; r < 8; ++r) p[r] = s_p[r];

    // --- phase B: partial matvec. thread = (cols c0..c0+1, d chunk dh) ---
    const int cg = t & 63;
    const int dh = t >> 6;            // 0..7
    const int c0 = cg * 2;
    float acc[8][2];
#pragma unroll
    for (int r = 0; r < 8; ++r) { acc[r][0] = 0.f; acc[r][1] = 0.f; }

    const float2* W2v = (const float2*)W2;
#pragma unroll
    for (int i = 0; i < 16; ++i) {
        const int d = dh * 16 + i;
        float2 w = W2v[(d * DD + c0) >> 1];
        float cbd = s_cb[d];
        float v1d = s_v1[d];
#pragma unroll
        for (int r = 0; r < 8; ++r) {
            float h = fmaxf(fmaf(p[r], v1d, cbd), 0.f);
            acc[r][0] = fmaf(h, w.x, acc[r][0]);
            acc[r][1] = fmaf(h, w.y, acc[r][1]);
        }
    }
#pragma unroll
    for (int r = 0; r < 8; ++r)
        *(float2*)&sP[(r * 8 + dh) * DD + c0] = make_float2(acc[r][0], acc[r][1]);
    __syncthreads();

    // --- phase C: combine. wave wv -> row wv; lane -> cols lane, lane+64 ---
    float s0 = 0.f, s1 = 0.f;
#pragma unroll
    for (int k = 0; k < 8; ++k) {
        const float* rowp = &sP[(wv * 8 + k) * DD];
        s0 += rowp[lane];
        s1 += rowp[lane + 64];
    }
    float f0 = fmaxf(s0 + b2[lane], 0.f);
    float f1 = fmaxf(s1 + b2[lane + 64], 0.f);

    const float2* Wc2 = (const float2*)Wc;
    float2 wa0 = Wc2[lane];
    float2 wa1 = Wc2[lane + 64];
    float2 wb0 = Wc2[DD + lane];
    float2 wb1 = Wc2[DD + lane + 64];

    float li0 = f0 * wa0.x + f1 * wa1.x;
    float li1 = f0 * wa0.y + f1 * wa1.y;
    float lj0 = f0 * wb0.x + f1 * wb1.x;
    float lj1 = f0 * wb0.y + f1 * wb1.y;

#pragma unroll
    for (int off = 32; off; off >>= 1) {
        li0 += __shfl_xor(li0, off, 64);
        li1 += __shfl_xor(li1, off, 64);
        lj0 += __shfl_xor(lj0, off, 64);
        lj1 += __shfl_xor(lj1, off, 64);
    }
    if (lane == 0) {
        int row = row0 + wv;
        *(float2*)&ws_li[row * 2] = make_float2(li0 + bc[0], li1 + bc[1]);
        *(float2*)&ws_lj[row * 2] = make_float2(lj0, lj1);
    }
}

// ---------------------------------------------------------------------------
// Kernel 2: logits[b,i,j,c] = li[b,i,c] + lj[b,j,c]   (bc pre-folded into li)
// Grid: 1024 blocks x 256 threads. Block covers 2 i-rows; thread stores 8 f32.
// ---------------------------------------------------------------------------
__global__ __launch_bounds__(256) void write_kernel(
    const float* __restrict__ ws_li,
    const float* __restrict__ ws_lj,
    float* __restrict__ out)
{
    const int blk = blockIdx.x;           // 0..1023
    const int t = threadIdx.x;
    const int b = blk >> 8;
    const int i = (blk & 255) * 2 + (t >> 7);
    const int j0 = (t & 127) * 4;

    float2 li = *(const float2*)&ws_li[(b * NN + i) * 2];
    float a0 = li.x;
    float a1 = li.y;

    float4 L0 = *(const float4*)&ws_lj[(b * NN + j0) * 2];       // rows j0, j0+1
    float4 L1 = *(const float4*)&ws_lj[(b * NN + j0 + 2) * 2];   // rows j0+2, j0+3

    float4 o0 = make_float4(a0 + L0.x, a1 + L0.y, a0 + L0.z, a1 + L0.w);
    float4 o1 = make_float4(a0 + L1.x, a1 + L1.y, a0 + L1.z, a1 + L1.w);

    size_t base = (((size_t)(b * NN + i)) * NN + j0) * 2;   // f32 element index
    *(float4*)&out[base]     = o0;
    *(float4*)&out[base + 4] = o1;
}

extern "C" void kernel_launch(void* const* d_in, const int* in_sizes, int n_in,
                              void* d_out, int out_size, void* d_ws, size_t ws_size,
                              hipStream_t stream) {
    const int*   adj = (const int*)d_in[0];
    const int*   tt  = (const int*)d_in[1];
    const float* te  = (const float*)d_in[2];
    const float* nc  = (const float*)d_in[3];
    const float* ee  = (const float*)d_in[4];
    const float* W1  = (const float*)d_in[5];
    const float* b1  = (const float*)d_in[6];
    const float* W2  = (const float*)d_in[7];
    const float* b2  = (const float*)d_in[8];
    const float* Wc  = (const float*)d_in[9];
    const float* bc  = (const float*)d_in[10];
    float* out = (float*)d_out;

    float* ws    = (float*)d_ws;
    float* ws_li = ws;            // 4096 floats
    float* ws_lj = ws + 4096;     // 4096 floats

    rows_kernel<<<256, 512, 0, stream>>>(adj, tt, te, nc, ee, W1, b1, W2, b2,
                                         Wc, bc, ws_li, ws_lj);
    write_kernel<<<1024, 256, 0, stream>>>(ws_li, ws_lj, out);
}